// Round 3
// baseline (811.752 us; speedup 1.0000x reference)
//
#include <hip/hip_runtime.h>

typedef unsigned short u16;
typedef unsigned int   u32;

#define N_MESH 50000
#define RA     40      // R*A
#define F_     32
#define OT     256     // O*T
#define KSELF  1280    // RA*F
#define KTOT   1312    // RA*F + F  (= 41*32 exactly)
#define NCH    41      // K chunks of 32
#define GN     32      // mesh rows per block (2 row-tiles of 16)
#define NBLK   1563    // ceil(50000/32); last block has 16 valid rows
#define SECC   5       // chunks per LDS section (sections: 5x8 + 1) -> LDS 20KB, 8 blk/CU

using f32x4 = __attribute__((ext_vector_type(4))) float;
using s16x8 = __attribute__((ext_vector_type(8))) short;   // 8 bf16 (4 VGPRs)

// Device-global scratch / flags (no dependence on ws_size).
__device__ __align__(16) u16 g_bhi[NCH * 16 * 64 * 8];      // B frags hi, 672 KB
__device__ __align__(16) u16 g_blo[NCH * 16 * 64 * 8];      // B frags lo, 672 KB
__device__ int g_isf32;

__device__ __forceinline__ float bf2f(u16 u) {
    union { u32 i; float f; } v; v.i = ((u32)u) << 16; return v.f;
}
__device__ __forceinline__ u16 f2bf(float f) {
    union { float f; u32 i; } v; v.f = f; u32 u = v.i;
    return (u16)((u + 0x7FFFu + ((u >> 16) & 1u)) >> 16);   // RNE
}
__device__ __forceinline__ float ld(const void* p, int i, int isf32) {
    return isf32 ? ((const float*)p)[i] : bf2f(((const u16*)p)[i]);
}

// split x into bf16 hi + bf16 lo (residual); pack pairs into u32
__device__ __forceinline__ void split2(float a, float b, u32& hp, u32& lp) {
    u16 ha = f2bf(a), hb = f2bf(b);
    u16 la = f2bf(a - bf2f(ha));
    u16 lb = f2bf(b - bf2f(hb));
    hp = (u32)ha | ((u32)hb << 16);
    lp = (u32)la | ((u32)lb << 16);
}
__device__ __forceinline__ f32x4 bf4(u32 p0, u32 p1) {
    f32x4 r;
    r.x = bf2f((u16)(p0 & 0xffffu)); r.y = bf2f((u16)(p0 >> 16));
    r.z = bf2f((u16)(p1 & 0xffffu)); r.w = bf2f((u16)(p1 >> 16));
    return r;
}

// Write one 8-element fragment run (hi+lo) to LDS at u16 index idx (16B aligned).
__device__ __forceinline__ void store_run(u16* __restrict__ Ah, u16* __restrict__ Al,
                                          int idx, f32x4 a, f32x4 b) {
    u32 h0,h1,h2,h3,l0,l1,l2,l3;
    split2(a.x, a.y, h0, l0);
    split2(a.z, a.w, h1, l1);
    split2(b.x, b.y, h2, l2);
    split2(b.z, b.w, h3, l3);
    *(uint4*)(Ah + idx) = make_uint4(h0,h1,h2,h3);
    *(uint4*)(Al + idx) = make_uint4(l0,l1,l2,l3);
}

// ---------------------------------------------------------------------------
// Dtype probe (parallelized): decode first 4096 u16 of mesh_signal as bf16.
// ---------------------------------------------------------------------------
__global__ void detect_kernel(const void* mesh) {
    __shared__ int s_weird;
    if (threadIdx.x == 0) s_weird = 0;
    __syncthreads();
    const u16* p = (const u16*)mesh;
    int w = 0;
    for (int j = threadIdx.x * 16; j < threadIdx.x * 16 + 16; ++j) {
        float v = bf2f(p[j]);
        float a = v < 0.f ? -v : v;
        if (!(a <= 1.0e6f)) ++w;
        else if (a > 0.f && a < 1.0e-30f) ++w;
    }
    atomicAdd(&s_weird, w);
    __syncthreads();
    if (threadIdx.x == 0) g_isf32 = (s_weird > 100) ? 1 : 0;
}

// ---------------------------------------------------------------------------
// Fused Weff + fragment pack. One thread per (k,c):
//   k <  1280 : w = sum_ra kernel[ra][k>>5] * W_neighbor[t][r][(a+o)&7][k&31]
//   k >= 1280 : w = W_self[t][k-1280]
// then split to bf16 hi/lo and write into MFMA B-fragment layout:
//   frag index = ((ch*16 + nt)*64 + (kg*16 + col))*8 + el
//   with ch=k>>5, kg=(k>>3)&3, el=k&7, nt=c>>4, col=c&15.
// ---------------------------------------------------------------------------
__global__ void weff_kernel(const void* __restrict__ Wn,
                            const void* __restrict__ Wself,
                            const void* __restrict__ ker) {
    int e = blockIdx.x * blockDim.x + threadIdx.x;
    if (e >= OT * KTOT) return;
    int isf32 = g_isf32;
    int c = e / KTOT;
    int k = e - c * KTOT;
    int t = c & 31;
    float acc = 0.f;
    if (k < KSELF) {
        int xy = k >> 5, f = k & 31;
        int o = c >> 5;
        for (int ra = 0; ra < RA; ++ra) {
            int r = ra >> 3, a = ra & 7;
            int a2 = (a + o) & 7;
            acc += ld(ker, ra * RA + xy, isf32) *
                   ld(Wn, t * (5 * 8 * F_) + r * (8 * F_) + a2 * F_ + f, isf32);
        }
    } else {
        acc = ld(Wself, t * F_ + (k - KSELF), isf32);
    }
    int ch = k >> 5;
    int kg = (k >> 3) & 3;
    int el = k & 7;
    int nt = c >> 4, col = c & 15;
    size_t fi = ((size_t)(ch * 16 + nt) * 64 + (kg * 16 + col)) * 8 + el;
    u16 h = f2bf(acc);
    u16 l = f2bf(acc - bf2f(h));
    g_bhi[fi] = h;
    g_blo[fi] = l;
}

// ---------------------------------------------------------------------------
// Main kernel. Per block: 32 mesh rows (2 row-tiles) x 256 outputs.
// Sections of <=5 K-chunks: phase1 gather+interp -> fragment-ordered LDS
// (bf16 hi/lo), phase2 MFMA (3x split: AhBh + AlBh + AhBl, fp32-equivalent).
// LDS = 20KB -> 8 blocks/CU (x 20KB = 160KB exactly); with VGPR<=64 that is
// 32 waves/CU, so the whole 1563-block grid is co-resident in ONE capacity
// wave (no tail) and gather latency is hidden by block-level TLP.
// ---------------------------------------------------------------------------
__global__ __launch_bounds__(256, 8)
void ConvIntrinsic_17102559772776_kernel(const void* __restrict__ mesh,
                                         const void* __restrict__ bary,
                                         const void* __restrict__ bias,
                                         void* __restrict__ out) {
    __shared__ __align__(16) u16 Ah[SECC * 2 * 64 * 8];   // 10 KB
    __shared__ __align__(16) u16 Al[SECC * 2 * 64 * 8];   // 10 KB

    const int tid   = threadIdx.x;
    const int n0    = blockIdx.x * GN;
    const int isf32 = g_isf32;
    const int lane  = tid & 63;
    const int wv    = tid >> 6;    // 0..3 : wave owns N-tiles wv*4 .. wv*4+3
    const int tn    = tid & 31;    // phase-1 row within block
    const int clt   = tid >> 5;    // phase-1 chunk-local 0..7 (active if < nch)

    f32x4 acc[2][4];
    #pragma unroll
    for (int rt = 0; rt < 2; ++rt)
        #pragma unroll
        for (int j = 0; j < 4; ++j) acc[rt][j] = (f32x4){0.f, 0.f, 0.f, 0.f};

    for (int sec = 0; sec < NCH; sec += SECC) {
        int nch = NCH - sec; if (nch > SECC) nch = SECC;

        // ---- phase 1: gather + interp -> fragment-ordered LDS (hi/lo) ----
        if (clt < nch) {
            const int ch   = sec + clt;
            const int gn   = n0 + tn;
            const int rt   = tn >> 4, lr = tn & 15;
            const int idx0 = ((clt * 2 + rt) * 64 + lr) * 8;   // + kg*128 per run
            if (gn >= N_MESH) {
                // tail block phantom rows: zero so MFMA stays finite
                #pragma unroll
                for (int kg = 0; kg < 4; ++kg) {
                    *(uint4*)(Ah + idx0 + kg * 128) = make_uint4(0,0,0,0);
                    *(uint4*)(Al + idx0 + kg * 128) = make_uint4(0,0,0,0);
                }
            } else if (ch < RA) {
                float fi0, w0, fi1, w1, fi2, w2;
                if (isf32) {
                    const float* bp = (const float*)bary + (size_t)gn * (RA * 6) + ch * 6;
                    fi0 = bp[0]; w0 = bp[1]; fi1 = bp[2]; w1 = bp[3]; fi2 = bp[4]; w2 = bp[5];
                } else {
                    const u16* bp = (const u16*)bary + (size_t)gn * (RA * 6) + ch * 6;
                    fi0 = bf2f(bp[0]); w0 = bf2f(bp[1]);
                    fi1 = bf2f(bp[2]); w1 = bf2f(bp[3]);
                    fi2 = bf2f(bp[4]); w2 = bf2f(bp[5]);
                }
                int i0 = (int)fi0, i1 = (int)fi1, i2 = (int)fi2;
                i0 = i0 < 0 ? 0 : (i0 > N_MESH - 1 ? N_MESH - 1 : i0);
                i1 = i1 < 0 ? 0 : (i1 > N_MESH - 1 ? N_MESH - 1 : i1);
                i2 = i2 < 0 ? 0 : (i2 > N_MESH - 1 ? N_MESH - 1 : i2);
                if (isf32) {
                    const f32x4* m0 = (const f32x4*)mesh + (size_t)i0 * 8;
                    const f32x4* m1 = (const f32x4*)mesh + (size_t)i1 * 8;
                    const f32x4* m2 = (const f32x4*)mesh + (size_t)i2 * 8;
                    #pragma unroll
                    for (int kg = 0; kg < 4; ++kg) {
                        f32x4 a = w0 * m0[2*kg]   + w1 * m1[2*kg]   + w2 * m2[2*kg];
                        f32x4 b = w0 * m0[2*kg+1] + w1 * m1[2*kg+1] + w2 * m2[2*kg+1];
                        store_run(Ah, Al, idx0 + kg * 128, a, b);
                    }
                } else {
                    const uint4* m0 = (const uint4*)mesh + (size_t)i0 * 4;
                    const uint4* m1 = (const uint4*)mesh + (size_t)i1 * 4;
                    const uint4* m2 = (const uint4*)mesh + (size_t)i2 * 4;
                    #pragma unroll
                    for (int kg = 0; kg < 4; ++kg) {
                        uint4 x0 = m0[kg], x1 = m1[kg], x2 = m2[kg];
                        f32x4 a = w0*bf4(x0.x,x0.y) + w1*bf4(x1.x,x1.y) + w2*bf4(x2.x,x2.y);
                        f32x4 b = w0*bf4(x0.z,x0.w) + w1*bf4(x1.z,x1.w) + w2*bf4(x2.z,x2.w);
                        store_run(Ah, Al, idx0 + kg * 128, a, b);
                    }
                }
            } else {
                // self chunk (k = 1280..1311): A = mesh[gn][f]
                if (isf32) {
                    const f32x4* ms = (const f32x4*)mesh + (size_t)gn * 8;
                    #pragma unroll
                    for (int kg = 0; kg < 4; ++kg)
                        store_run(Ah, Al, idx0 + kg * 128, ms[2*kg], ms[2*kg+1]);
                } else {
                    const uint4* ms = (const uint4*)mesh + (size_t)gn * 4;
                    #pragma unroll
                    for (int kg = 0; kg < 4; ++kg) {
                        uint4 x = ms[kg];
                        store_run(Ah, Al, idx0 + kg * 128, bf4(x.x,x.y), bf4(x.z,x.w));
                    }
                }
            }
        }
        __syncthreads();

        // ---- phase 2: MFMA over this section's chunks; B reused for 2 row-tiles ----
        #pragma unroll 2
        for (int c = 0; c < nch; ++c) {
            int ch = sec + c;
            size_t bo = ((size_t)(ch * 16 + wv * 4) * 64 + lane) * 8;
            const s16x8* bh = (const s16x8*)&g_bhi[bo];
            const s16x8* bl = (const s16x8*)&g_blo[bo];
            s16x8 bhj[4], blj[4];
            #pragma unroll
            for (int j = 0; j < 4; ++j) { bhj[j] = bh[j * 64]; blj[j] = bl[j * 64]; }
            #pragma unroll
            for (int rt = 0; rt < 2; ++rt) {
                s16x8 ah = *(const s16x8*)&Ah[((c * 2 + rt) * 64 + lane) * 8];
                s16x8 al = *(const s16x8*)&Al[((c * 2 + rt) * 64 + lane) * 8];
                #pragma unroll
                for (int j = 0; j < 4; ++j) {
                    acc[rt][j] = __builtin_amdgcn_mfma_f32_16x16x32_bf16(ah, bhj[j], acc[rt][j], 0, 0, 0);
                    acc[rt][j] = __builtin_amdgcn_mfma_f32_16x16x32_bf16(al, bhj[j], acc[rt][j], 0, 0, 0);
                    acc[rt][j] = __builtin_amdgcn_mfma_f32_16x16x32_bf16(ah, blj[j], acc[rt][j], 0, 0, 0);
                }
            }
        }
        __syncthreads();
    }

    // ---- epilogue: C/D layout col=lane&15, row=(lane>>4)*4+reg [m89] ----
    const int col = lane & 15, rg = lane >> 4;
    #pragma unroll
    for (int j = 0; j < 4; ++j) {
        int c = (wv * 4 + j) * 16 + col;
        float bv = ld(bias, c & 31, isf32);
        #pragma unroll
        for (int rt = 0; rt < 2; ++rt) {
            #pragma unroll
            for (int r = 0; r < 4; ++r) {
                int row = n0 + rt * 16 + rg * 4 + r;
                if (row < N_MESH) {
                    float v = acc[rt][j][r] + bv;
                    v = v > 0.f ? v : 0.f;
                    size_t oi = (size_t)row * OT + c;
                    if (isf32) ((float*)out)[oi] = v;
                    else       ((u16*)out)[oi]   = f2bf(v);
                }
            }
        }
    }
}

extern "C" void kernel_launch(void* const* d_in, const int* in_sizes, int n_in,
                              void* d_out, int out_size, void* d_ws, size_t ws_size,
                              hipStream_t stream) {
    const void* mesh  = d_in[0];
    const void* bary  = d_in[1];
    const void* Wself = d_in[2];
    const void* Wn    = d_in[3];
    const void* bias  = d_in[4];
    const void* ker   = d_in[5];
    (void)in_sizes; (void)n_in; (void)out_size; (void)d_ws; (void)ws_size;

    detect_kernel<<<1, 256, 0, stream>>>(mesh);

    {
        int total  = OT * KTOT;
        int blocks = (total + 255) / 256;
        weff_kernel<<<blocks, 256, 0, stream>>>(Wn, Wself, ker);
    }

    ConvIntrinsic_17102559772776_kernel<<<NBLK, 256, 0, stream>>>(mesh, bary, bias, d_out);
}

// Round 4
// 368.407 us; speedup vs baseline: 2.2034x; 2.2034x over previous
//
#include <hip/hip_runtime.h>

typedef unsigned short u16;
typedef unsigned int   u32;

#define N_MESH 50000
#define RA     40      // R*A
#define F_     32
#define OT     256     // O*T
#define KSELF  1280    // RA*F
#define KTOT   1312    // RA*F + F  (= 41*32 exactly)
#define NCH    41      // K chunks of 32
#define GN     32      // mesh rows per block (2 row-tiles of 16)
#define NBLK   1563    // ceil(50000/32); last block has 16 valid rows
#define SECC   5       // chunks per LDS section -> LDS 20KB, 8 blk/CU by LDS

using f32x4 = __attribute__((ext_vector_type(4))) float;
using s16x8 = __attribute__((ext_vector_type(8))) short;   // 8 bf16 (4 VGPRs)

// Device-global scratch / flags (no dependence on ws_size).
__device__ __align__(16) u16 g_bhi[NCH * 16 * 64 * 8];      // B frags hi, 672 KB
__device__ __align__(16) u16 g_blo[NCH * 16 * 64 * 8];      // B frags lo, 672 KB
__device__ int g_isf32;

__device__ __forceinline__ float bf2f(u16 u) {
    union { u32 i; float f; } v; v.i = ((u32)u) << 16; return v.f;
}
__device__ __forceinline__ u16 f2bf(float f) {
    union { float f; u32 i; } v; v.f = f; u32 u = v.i;
    return (u16)((u + 0x7FFFu + ((u >> 16) & 1u)) >> 16);   // RNE
}
__device__ __forceinline__ float ld(const void* p, int i, int isf32) {
    return isf32 ? ((const float*)p)[i] : bf2f(((const u16*)p)[i]);
}

// split x into bf16 hi + bf16 lo (residual); pack pairs into u32
__device__ __forceinline__ void split2(float a, float b, u32& hp, u32& lp) {
    u16 ha = f2bf(a), hb = f2bf(b);
    u16 la = f2bf(a - bf2f(ha));
    u16 lb = f2bf(b - bf2f(hb));
    hp = (u32)ha | ((u32)hb << 16);
    lp = (u32)la | ((u32)lb << 16);
}
__device__ __forceinline__ f32x4 bf4(u32 p0, u32 p1) {
    f32x4 r;
    r.x = bf2f((u16)(p0 & 0xffffu)); r.y = bf2f((u16)(p0 >> 16));
    r.z = bf2f((u16)(p1 & 0xffffu)); r.w = bf2f((u16)(p1 >> 16));
    return r;
}

// Write one 8-element fragment run (hi+lo) to LDS at u16 index idx (16B aligned).
__device__ __forceinline__ void store_run(u16* __restrict__ Ah, u16* __restrict__ Al,
                                          int idx, f32x4 a, f32x4 b) {
    u32 h0,h1,h2,h3,l0,l1,l2,l3;
    split2(a.x, a.y, h0, l0);
    split2(a.z, a.w, h1, l1);
    split2(b.x, b.y, h2, l2);
    split2(b.z, b.w, h3, l3);
    *(uint4*)(Ah + idx) = make_uint4(h0,h1,h2,h3);
    *(uint4*)(Al + idx) = make_uint4(l0,l1,l2,l3);
}

// ---------------------------------------------------------------------------
// Dtype probe (parallelized): decode first 4096 u16 of mesh_signal as bf16.
// ---------------------------------------------------------------------------
__global__ void detect_kernel(const void* mesh) {
    __shared__ int s_weird;
    if (threadIdx.x == 0) s_weird = 0;
    __syncthreads();
    const u16* p = (const u16*)mesh;
    int w = 0;
    for (int j = threadIdx.x * 16; j < threadIdx.x * 16 + 16; ++j) {
        float v = bf2f(p[j]);
        float a = v < 0.f ? -v : v;
        if (!(a <= 1.0e6f)) ++w;
        else if (a > 0.f && a < 1.0e-30f) ++w;
    }
    atomicAdd(&s_weird, w);
    __syncthreads();
    if (threadIdx.x == 0) g_isf32 = (s_weird > 100) ? 1 : 0;
}

// ---------------------------------------------------------------------------
// Fused Weff + fragment pack. One thread per (k,c):
//   k <  1280 : w = sum_ra kernel[ra][k>>5] * W_neighbor[t][r][(a+o)&7][k&31]
//   k >= 1280 : w = W_self[t][k-1280]
// then split to bf16 hi/lo and write into MFMA B-fragment layout:
//   frag index = ((ch*16 + nt)*64 + (kg*16 + col))*8 + el
//   with ch=k>>5, kg=(k>>3)&3, el=k&7, nt=c>>4, col=c&15.
// ---------------------------------------------------------------------------
__global__ void weff_kernel(const void* __restrict__ Wn,
                            const void* __restrict__ Wself,
                            const void* __restrict__ ker) {
    int e = blockIdx.x * blockDim.x + threadIdx.x;
    if (e >= OT * KTOT) return;
    int isf32 = g_isf32;
    int c = e / KTOT;
    int k = e - c * KTOT;
    int t = c & 31;
    float acc = 0.f;
    if (k < KSELF) {
        int xy = k >> 5, f = k & 31;
        int o = c >> 5;
        for (int ra = 0; ra < RA; ++ra) {
            int r = ra >> 3, a = ra & 7;
            int a2 = (a + o) & 7;
            acc += ld(ker, ra * RA + xy, isf32) *
                   ld(Wn, t * (5 * 8 * F_) + r * (8 * F_) + a2 * F_ + f, isf32);
        }
    } else {
        acc = ld(Wself, t * F_ + (k - KSELF), isf32);
    }
    int ch = k >> 5;
    int kg = (k >> 3) & 3;
    int el = k & 7;
    int nt = c >> 4, col = c & 15;
    size_t fi = ((size_t)(ch * 16 + nt) * 64 + (kg * 16 + col)) * 8 + el;
    u16 h = f2bf(acc);
    u16 l = f2bf(acc - bf2f(h));
    g_bhi[fi] = h;
    g_blo[fi] = l;
}

// ---------------------------------------------------------------------------
// Main kernel. Per block: 32 mesh rows (2 row-tiles) x 256 outputs.
// Sections of <=5 K-chunks: phase1 gather+interp -> fragment-ordered LDS
// (bf16 hi/lo), phase2 MFMA (3x split: AhBh + AlBh + AhBl, fp32-equivalent).
// LDS = 20KB -> 8 blocks/CU by LDS. launch_bounds(256,4): round 2 showed the
// compiler allocates exactly 64 VGPR under this bound, and 64 VGPR already
// permits 8 waves/SIMD -> 8 blocks/CU. (256,8) FORCED 32 VGPR and spilled the
// accumulators to scratch: FETCH 263MB->1.6GB, 714us. Do not cap below 64.
// ---------------------------------------------------------------------------
__global__ __launch_bounds__(256, 4)
void ConvIntrinsic_17102559772776_kernel(const void* __restrict__ mesh,
                                         const void* __restrict__ bary,
                                         const void* __restrict__ bias,
                                         void* __restrict__ out) {
    __shared__ __align__(16) u16 Ah[SECC * 2 * 64 * 8];   // 10 KB
    __shared__ __align__(16) u16 Al[SECC * 2 * 64 * 8];   // 10 KB

    const int tid   = threadIdx.x;
    const int n0    = blockIdx.x * GN;
    const int isf32 = g_isf32;
    const int lane  = tid & 63;
    const int wv    = tid >> 6;    // 0..3 : wave owns N-tiles wv*4 .. wv*4+3
    const int tn    = tid & 31;    // phase-1 row within block
    const int clt   = tid >> 5;    // phase-1 chunk-local 0..7 (active if < nch)

    f32x4 acc[2][4];
    #pragma unroll
    for (int rt = 0; rt < 2; ++rt)
        #pragma unroll
        for (int j = 0; j < 4; ++j) acc[rt][j] = (f32x4){0.f, 0.f, 0.f, 0.f};

    for (int sec = 0; sec < NCH; sec += SECC) {
        int nch = NCH - sec; if (nch > SECC) nch = SECC;

        // ---- phase 1: gather + interp -> fragment-ordered LDS (hi/lo) ----
        if (clt < nch) {
            const int ch   = sec + clt;
            const int gn   = n0 + tn;
            const int rt   = tn >> 4, lr = tn & 15;
            const int idx0 = ((clt * 2 + rt) * 64 + lr) * 8;   // + kg*128 per run
            if (gn >= N_MESH) {
                // tail block phantom rows: zero so MFMA stays finite
                #pragma unroll
                for (int kg = 0; kg < 4; ++kg) {
                    *(uint4*)(Ah + idx0 + kg * 128) = make_uint4(0,0,0,0);
                    *(uint4*)(Al + idx0 + kg * 128) = make_uint4(0,0,0,0);
                }
            } else if (ch < RA) {
                float fi0, w0, fi1, w1, fi2, w2;
                if (isf32) {
                    const float* bp = (const float*)bary + (size_t)gn * (RA * 6) + ch * 6;
                    fi0 = bp[0]; w0 = bp[1]; fi1 = bp[2]; w1 = bp[3]; fi2 = bp[4]; w2 = bp[5];
                } else {
                    const u16* bp = (const u16*)bary + (size_t)gn * (RA * 6) + ch * 6;
                    fi0 = bf2f(bp[0]); w0 = bf2f(bp[1]);
                    fi1 = bf2f(bp[2]); w1 = bf2f(bp[3]);
                    fi2 = bf2f(bp[4]); w2 = bf2f(bp[5]);
                }
                int i0 = (int)fi0, i1 = (int)fi1, i2 = (int)fi2;
                i0 = i0 < 0 ? 0 : (i0 > N_MESH - 1 ? N_MESH - 1 : i0);
                i1 = i1 < 0 ? 0 : (i1 > N_MESH - 1 ? N_MESH - 1 : i1);
                i2 = i2 < 0 ? 0 : (i2 > N_MESH - 1 ? N_MESH - 1 : i2);
                if (isf32) {
                    const f32x4* m0 = (const f32x4*)mesh + (size_t)i0 * 8;
                    const f32x4* m1 = (const f32x4*)mesh + (size_t)i1 * 8;
                    const f32x4* m2 = (const f32x4*)mesh + (size_t)i2 * 8;
                    #pragma unroll
                    for (int kg = 0; kg < 4; ++kg) {
                        f32x4 a = w0 * m0[2*kg]   + w1 * m1[2*kg]   + w2 * m2[2*kg];
                        f32x4 b = w0 * m0[2*kg+1] + w1 * m1[2*kg+1] + w2 * m2[2*kg+1];
                        store_run(Ah, Al, idx0 + kg * 128, a, b);
                    }
                } else {
                    const uint4* m0 = (const uint4*)mesh + (size_t)i0 * 4;
                    const uint4* m1 = (const uint4*)mesh + (size_t)i1 * 4;
                    const uint4* m2 = (const uint4*)mesh + (size_t)i2 * 4;
                    #pragma unroll
                    for (int kg = 0; kg < 4; ++kg) {
                        uint4 x0 = m0[kg], x1 = m1[kg], x2 = m2[kg];
                        f32x4 a = w0*bf4(x0.x,x0.y) + w1*bf4(x1.x,x1.y) + w2*bf4(x2.x,x2.y);
                        f32x4 b = w0*bf4(x0.z,x0.w) + w1*bf4(x1.z,x1.w) + w2*bf4(x2.z,x2.w);
                        store_run(Ah, Al, idx0 + kg * 128, a, b);
                    }
                }
            } else {
                // self chunk (k = 1280..1311): A = mesh[gn][f]
                if (isf32) {
                    const f32x4* ms = (const f32x4*)mesh + (size_t)gn * 8;
                    #pragma unroll
                    for (int kg = 0; kg < 4; ++kg)
                        store_run(Ah, Al, idx0 + kg * 128, ms[2*kg], ms[2*kg+1]);
                } else {
                    const uint4* ms = (const uint4*)mesh + (size_t)gn * 4;
                    #pragma unroll
                    for (int kg = 0; kg < 4; ++kg) {
                        uint4 x = ms[kg];
                        store_run(Ah, Al, idx0 + kg * 128, bf4(x.x,x.y), bf4(x.z,x.w));
                    }
                }
            }
        }
        __syncthreads();

        // ---- phase 2: MFMA over this section's chunks; B reused for 2 row-tiles ----
        #pragma unroll 2
        for (int c = 0; c < nch; ++c) {
            int ch = sec + c;
            size_t bo = ((size_t)(ch * 16 + wv * 4) * 64 + lane) * 8;
            const s16x8* bh = (const s16x8*)&g_bhi[bo];
            const s16x8* bl = (const s16x8*)&g_blo[bo];
            s16x8 bhj[4], blj[4];
            #pragma unroll
            for (int j = 0; j < 4; ++j) { bhj[j] = bh[j * 64]; blj[j] = bl[j * 64]; }
            #pragma unroll
            for (int rt = 0; rt < 2; ++rt) {
                s16x8 ah = *(const s16x8*)&Ah[((c * 2 + rt) * 64 + lane) * 8];
                s16x8 al = *(const s16x8*)&Al[((c * 2 + rt) * 64 + lane) * 8];
                #pragma unroll
                for (int j = 0; j < 4; ++j) {
                    acc[rt][j] = __builtin_amdgcn_mfma_f32_16x16x32_bf16(ah, bhj[j], acc[rt][j], 0, 0, 0);
                    acc[rt][j] = __builtin_amdgcn_mfma_f32_16x16x32_bf16(al, bhj[j], acc[rt][j], 0, 0, 0);
                    acc[rt][j] = __builtin_amdgcn_mfma_f32_16x16x32_bf16(ah, blj[j], acc[rt][j], 0, 0, 0);
                }
            }
        }
        __syncthreads();
    }

    // ---- epilogue: C/D layout col=lane&15, row=(lane>>4)*4+reg [m89] ----
    const int col = lane & 15, rg = lane >> 4;
    #pragma unroll
    for (int j = 0; j < 4; ++j) {
        int c = (wv * 4 + j) * 16 + col;
        float bv = ld(bias, c & 31, isf32);
        #pragma unroll
        for (int rt = 0; rt < 2; ++rt) {
            #pragma unroll
            for (int r = 0; r < 4; ++r) {
                int row = n0 + rt * 16 + rg * 4 + r;
                if (row < N_MESH) {
                    float v = acc[rt][j][r] + bv;
                    v = v > 0.f ? v : 0.f;
                    size_t oi = (size_t)row * OT + c;
                    if (isf32) ((float*)out)[oi] = v;
                    else       ((u16*)out)[oi]   = f2bf(v);
                }
            }
        }
    }
}

extern "C" void kernel_launch(void* const* d_in, const int* in_sizes, int n_in,
                              void* d_out, int out_size, void* d_ws, size_t ws_size,
                              hipStream_t stream) {
    const void* mesh  = d_in[0];
    const void* bary  = d_in[1];
    const void* Wself = d_in[2];
    const void* Wn    = d_in[3];
    const void* bias  = d_in[4];
    const void* ker   = d_in[5];
    (void)in_sizes; (void)n_in; (void)out_size; (void)d_ws; (void)ws_size;

    detect_kernel<<<1, 256, 0, stream>>>(mesh);

    {
        int total  = OT * KTOT;
        int blocks = (total + 255) / 256;
        weff_kernel<<<blocks, 256, 0, stream>>>(Wn, Wself, ker);
    }

    ConvIntrinsic_17102559772776_kernel<<<NBLK, 256, 0, stream>>>(mesh, bary, bias, d_out);
}

// Round 5
// 304.601 us; speedup vs baseline: 2.6650x; 1.2095x over previous
//
#include <hip/hip_runtime.h>

typedef unsigned short u16;
typedef unsigned int   u32;

#define N_MESH 50000
#define RA     40      // R*A
#define F_     32
#define OT     256     // O*T
#define KSELF  1280    // RA*F
#define KTOT   1312    // RA*F + F  (= 41*32 exactly)
#define NCH    41      // K chunks of 32
#define GN     32      // mesh rows per block (2 row-tiles of 16)
#define NBLK   1563    // ceil(50000/32); last block has 16 valid rows
#define SECC   8       // chunks per LDS section (round-2 best config: 264us)

using f32x4 = __attribute__((ext_vector_type(4))) float;
using s16x8 = __attribute__((ext_vector_type(8))) short;   // 8 bf16 (4 VGPRs)

// Device-global scratch / flags (no dependence on ws_size).
__device__ __align__(16) u16 g_bhi[NCH * 16 * 64 * 8];      // B frags hi, 672 KB
__device__ __align__(16) u16 g_blo[NCH * 16 * 64 * 8];      // B frags lo, 672 KB
__device__ __align__(16) u16 g_mesh16[N_MESH * F_];         // fp16 mesh shadow, 3.2 MB (< 4MB L2/XCD)
__device__ int g_isf32;

__device__ __forceinline__ float bf2f(u16 u) {
    union { u32 i; float f; } v; v.i = ((u32)u) << 16; return v.f;
}
__device__ __forceinline__ u16 f2bf(float f) {
    union { float f; u32 i; } v; v.f = f; u32 u = v.i;
    return (u16)((u + 0x7FFFu + ((u >> 16) & 1u)) >> 16);   // RNE
}
__device__ __forceinline__ float ld(const void* p, int i, int isf32) {
    return isf32 ? ((const float*)p)[i] : bf2f(((const u16*)p)[i]);
}

// split x into bf16 hi + bf16 lo (residual); pack pairs into u32
__device__ __forceinline__ void split2(float a, float b, u32& hp, u32& lp) {
    u16 ha = f2bf(a), hb = f2bf(b);
    u16 la = f2bf(a - bf2f(ha));
    u16 lb = f2bf(b - bf2f(hb));
    hp = (u32)ha | ((u32)hb << 16);
    lp = (u32)la | ((u32)lb << 16);
}
// 4 packed fp16 -> 4 fp32
__device__ __forceinline__ f32x4 h4(u32 p0, u32 p1) {
    union { u32 u; _Float16 h[2]; } a, b;
    a.u = p0; b.u = p1;
    f32x4 r;
    r.x = (float)a.h[0]; r.y = (float)a.h[1];
    r.z = (float)b.h[0]; r.w = (float)b.h[1];
    return r;
}

// Write one 8-element fragment run (hi+lo) to LDS at u16 index idx (16B aligned).
__device__ __forceinline__ void store_run(u16* __restrict__ Ah, u16* __restrict__ Al,
                                          int idx, f32x4 a, f32x4 b) {
    u32 h0,h1,h2,h3,l0,l1,l2,l3;
    split2(a.x, a.y, h0, l0);
    split2(a.z, a.w, h1, l1);
    split2(b.x, b.y, h2, l2);
    split2(b.z, b.w, h3, l3);
    *(uint4*)(Ah + idx) = make_uint4(h0,h1,h2,h3);
    *(uint4*)(Al + idx) = make_uint4(l0,l1,l2,l3);
}

// ---------------------------------------------------------------------------
// Dtype probe (parallelized): decode first 4096 u16 of mesh_signal as bf16.
// ---------------------------------------------------------------------------
__global__ void detect_kernel(const void* mesh) {
    __shared__ int s_weird;
    if (threadIdx.x == 0) s_weird = 0;
    __syncthreads();
    const u16* p = (const u16*)mesh;
    int w = 0;
    for (int j = threadIdx.x * 16; j < threadIdx.x * 16 + 16; ++j) {
        float v = bf2f(p[j]);
        float a = v < 0.f ? -v : v;
        if (!(a <= 1.0e6f)) ++w;
        else if (a > 0.f && a < 1.0e-30f) ++w;
    }
    atomicAdd(&s_weird, w);
    __syncthreads();
    if (threadIdx.x == 0) g_isf32 = (s_weird > 100) ? 1 : 0;
}

// ---------------------------------------------------------------------------
// fp16 mesh shadow: 3.2 MB fits each XCD's 4 MB L2, so the 6M random row
// gathers in phase 1 become L2 hits instead of ~38% fabric misses (fp32 mesh
// is 6.4 MB -> thrash). fp16 adds <=2^-11 relative noise on interp inputs.
// ---------------------------------------------------------------------------
__global__ void mesh16_kernel(const void* __restrict__ mesh) {
    int i = blockIdx.x * blockDim.x + threadIdx.x;   // one thread per 8 elems
    if (i >= N_MESH * F_ / 8) return;
    int isf32 = g_isf32;
    union { uint4 v; _Float16 h[8]; } o;
    #pragma unroll
    for (int j = 0; j < 8; ++j)
        o.h[j] = (_Float16)ld(mesh, i * 8 + j, isf32);
    *((uint4*)g_mesh16 + i) = o.v;
}

// ---------------------------------------------------------------------------
// Fused Weff + fragment pack. One thread per (k,c):
//   k <  1280 : w = sum_ra kernel[ra][k>>5] * W_neighbor[t][r][(a+o)&7][k&31]
//   k >= 1280 : w = W_self[t][k-1280]
// then split to bf16 hi/lo and write into MFMA B-fragment layout:
//   frag index = ((ch*16 + nt)*64 + (kg*16 + col))*8 + el
//   with ch=k>>5, kg=(k>>3)&3, el=k&7, nt=c>>4, col=c&15.
// ---------------------------------------------------------------------------
__global__ void weff_kernel(const void* __restrict__ Wn,
                            const void* __restrict__ Wself,
                            const void* __restrict__ ker) {
    int e = blockIdx.x * blockDim.x + threadIdx.x;
    if (e >= OT * KTOT) return;
    int isf32 = g_isf32;
    int c = e / KTOT;
    int k = e - c * KTOT;
    int t = c & 31;
    float acc = 0.f;
    if (k < KSELF) {
        int xy = k >> 5, f = k & 31;
        int o = c >> 5;
        for (int ra = 0; ra < RA; ++ra) {
            int r = ra >> 3, a = ra & 7;
            int a2 = (a + o) & 7;
            acc += ld(ker, ra * RA + xy, isf32) *
                   ld(Wn, t * (5 * 8 * F_) + r * (8 * F_) + a2 * F_ + f, isf32);
        }
    } else {
        acc = ld(Wself, t * F_ + (k - KSELF), isf32);
    }
    int ch = k >> 5;
    int kg = (k >> 3) & 3;
    int el = k & 7;
    int nt = c >> 4, col = c & 15;
    size_t fi = ((size_t)(ch * 16 + nt) * 64 + (kg * 16 + col)) * 8 + el;
    u16 h = f2bf(acc);
    u16 l = f2bf(acc - bf2f(h));
    g_bhi[fi] = h;
    g_blo[fi] = l;
}

// ---------------------------------------------------------------------------
// Main kernel. Per block: 32 mesh rows (2 row-tiles) x 256 outputs.
// Sections of <=8 K-chunks: phase1 gather(fp16 shadow)+interp -> fragment-
// ordered LDS (bf16 hi/lo), phase2 MFMA (3x split: AhBh+AlBh+AhBl).
// Occupancy: reg file caps at 4 waves/SIMD (64 VGPR + 32 AGPR acc ~ 96-128
// unified regs) -> 4 blocks/CU; LDS 32 KB x 4 = 128 KB fits. Do NOT use
// launch_bounds(256,8): it forces 32 VGPR and spills acc (round 3: 714us).
// ---------------------------------------------------------------------------
__global__ __launch_bounds__(256, 4)
void ConvIntrinsic_17102559772776_kernel(const void* __restrict__ mesh,
                                         const void* __restrict__ bary,
                                         const void* __restrict__ bias,
                                         void* __restrict__ out) {
    __shared__ __align__(16) u16 Ah[SECC * 2 * 64 * 8];   // 16 KB
    __shared__ __align__(16) u16 Al[SECC * 2 * 64 * 8];   // 16 KB

    const int tid   = threadIdx.x;
    const int n0    = blockIdx.x * GN;
    const int isf32 = g_isf32;
    const int lane  = tid & 63;
    const int wv    = tid >> 6;    // 0..3 : wave owns N-tiles wv*4 .. wv*4+3
    const int tn    = tid & 31;    // phase-1 row within block
    const int clt   = tid >> 5;    // phase-1 chunk-local 0..7 (active if < nch)

    f32x4 acc[2][4];
    #pragma unroll
    for (int rt = 0; rt < 2; ++rt)
        #pragma unroll
        for (int j = 0; j < 4; ++j) acc[rt][j] = (f32x4){0.f, 0.f, 0.f, 0.f};

    for (int sec = 0; sec < NCH; sec += SECC) {
        int nch = NCH - sec; if (nch > SECC) nch = SECC;

        // ---- phase 1: gather + interp -> fragment-ordered LDS (hi/lo) ----
        if (clt < nch) {
            const int ch   = sec + clt;
            const int gn   = n0 + tn;
            const int rt   = tn >> 4, lr = tn & 15;
            const int idx0 = ((clt * 2 + rt) * 64 + lr) * 8;   // + kg*128 per run
            if (gn >= N_MESH) {
                // tail block phantom rows: zero so MFMA stays finite
                #pragma unroll
                for (int kg = 0; kg < 4; ++kg) {
                    *(uint4*)(Ah + idx0 + kg * 128) = make_uint4(0,0,0,0);
                    *(uint4*)(Al + idx0 + kg * 128) = make_uint4(0,0,0,0);
                }
            } else if (ch < RA) {
                float fi0, w0, fi1, w1, fi2, w2;
                if (isf32) {
                    const float* bp = (const float*)bary + (size_t)gn * (RA * 6) + ch * 6;
                    fi0 = bp[0]; w0 = bp[1]; fi1 = bp[2]; w1 = bp[3]; fi2 = bp[4]; w2 = bp[5];
                } else {
                    const u16* bp = (const u16*)bary + (size_t)gn * (RA * 6) + ch * 6;
                    fi0 = bf2f(bp[0]); w0 = bf2f(bp[1]);
                    fi1 = bf2f(bp[2]); w1 = bf2f(bp[3]);
                    fi2 = bf2f(bp[4]); w2 = bf2f(bp[5]);
                }
                int i0 = (int)fi0, i1 = (int)fi1, i2 = (int)fi2;
                i0 = i0 < 0 ? 0 : (i0 > N_MESH - 1 ? N_MESH - 1 : i0);
                i1 = i1 < 0 ? 0 : (i1 > N_MESH - 1 ? N_MESH - 1 : i1);
                i2 = i2 < 0 ? 0 : (i2 > N_MESH - 1 ? N_MESH - 1 : i2);
                // fp16 shadow rows: 64 B each, L2-resident
                const uint4* m0 = (const uint4*)g_mesh16 + (size_t)i0 * 4;
                const uint4* m1 = (const uint4*)g_mesh16 + (size_t)i1 * 4;
                const uint4* m2 = (const uint4*)g_mesh16 + (size_t)i2 * 4;
                #pragma unroll
                for (int kg = 0; kg < 4; ++kg) {
                    uint4 x0 = m0[kg], x1 = m1[kg], x2 = m2[kg];
                    f32x4 a = w0*h4(x0.x,x0.y) + w1*h4(x1.x,x1.y) + w2*h4(x2.x,x2.y);
                    f32x4 b = w0*h4(x0.z,x0.w) + w1*h4(x1.z,x1.w) + w2*h4(x2.z,x2.w);
                    store_run(Ah, Al, idx0 + kg * 128, a, b);
                }
            } else {
                // self chunk (k = 1280..1311): A = mesh[gn][f], full precision
                if (isf32) {
                    const f32x4* ms = (const f32x4*)mesh + (size_t)gn * 8;
                    #pragma unroll
                    for (int kg = 0; kg < 4; ++kg)
                        store_run(Ah, Al, idx0 + kg * 128, ms[2*kg], ms[2*kg+1]);
                } else {
                    const uint4* ms = (const uint4*)mesh + (size_t)gn * 4;
                    #pragma unroll
                    for (int kg = 0; kg < 4; ++kg) {
                        uint4 x = ms[kg];
                        f32x4 a, b;
                        a.x = bf2f((u16)(x.x & 0xffffu)); a.y = bf2f((u16)(x.x >> 16));
                        a.z = bf2f((u16)(x.y & 0xffffu)); a.w = bf2f((u16)(x.y >> 16));
                        b.x = bf2f((u16)(x.z & 0xffffu)); b.y = bf2f((u16)(x.z >> 16));
                        b.z = bf2f((u16)(x.w & 0xffffu)); b.w = bf2f((u16)(x.w >> 16));
                        store_run(Ah, Al, idx0 + kg * 128, a, b);
                    }
                }
            }
        }
        __syncthreads();

        // ---- phase 2: MFMA over this section's chunks; B reused for 2 row-tiles ----
        #pragma unroll 2
        for (int c = 0; c < nch; ++c) {
            int ch = sec + c;
            size_t bo = ((size_t)(ch * 16 + wv * 4) * 64 + lane) * 8;
            const s16x8* bh = (const s16x8*)&g_bhi[bo];
            const s16x8* bl = (const s16x8*)&g_blo[bo];
            s16x8 bhj[4], blj[4];
            #pragma unroll
            for (int j = 0; j < 4; ++j) { bhj[j] = bh[j * 64]; blj[j] = bl[j * 64]; }
            #pragma unroll
            for (int rt = 0; rt < 2; ++rt) {
                s16x8 ah = *(const s16x8*)&Ah[((c * 2 + rt) * 64 + lane) * 8];
                s16x8 al = *(const s16x8*)&Al[((c * 2 + rt) * 64 + lane) * 8];
                #pragma unroll
                for (int j = 0; j < 4; ++j) {
                    acc[rt][j] = __builtin_amdgcn_mfma_f32_16x16x32_bf16(ah, bhj[j], acc[rt][j], 0, 0, 0);
                    acc[rt][j] = __builtin_amdgcn_mfma_f32_16x16x32_bf16(al, bhj[j], acc[rt][j], 0, 0, 0);
                    acc[rt][j] = __builtin_amdgcn_mfma_f32_16x16x32_bf16(ah, blj[j], acc[rt][j], 0, 0, 0);
                }
            }
        }
        __syncthreads();
    }

    // ---- epilogue: C/D layout col=lane&15, row=(lane>>4)*4+reg [m89] ----
    const int col = lane & 15, rg = lane >> 4;
    #pragma unroll
    for (int j = 0; j < 4; ++j) {
        int c = (wv * 4 + j) * 16 + col;
        float bv = ld(bias, c & 31, isf32);
        #pragma unroll
        for (int rt = 0; rt < 2; ++rt) {
            #pragma unroll
            for (int r = 0; r < 4; ++r) {
                int row = n0 + rt * 16 + rg * 4 + r;
                if (row < N_MESH) {
                    float v = acc[rt][j][r] + bv;
                    v = v > 0.f ? v : 0.f;
                    size_t oi = (size_t)row * OT + c;
                    if (isf32) ((float*)out)[oi] = v;
                    else       ((u16*)out)[oi]   = f2bf(v);
                }
            }
        }
    }
}

extern "C" void kernel_launch(void* const* d_in, const int* in_sizes, int n_in,
                              void* d_out, int out_size, void* d_ws, size_t ws_size,
                              hipStream_t stream) {
    const void* mesh  = d_in[0];
    const void* bary  = d_in[1];
    const void* Wself = d_in[2];
    const void* Wn    = d_in[3];
    const void* bias  = d_in[4];
    const void* ker   = d_in[5];
    (void)in_sizes; (void)n_in; (void)out_size; (void)d_ws; (void)ws_size;

    detect_kernel<<<1, 256, 0, stream>>>(mesh);

    {
        int total  = N_MESH * F_ / 8;
        int blocks = (total + 255) / 256;
        mesh16_kernel<<<blocks, 256, 0, stream>>>(mesh);
    }
    {
        int total  = OT * KTOT;
        int blocks = (total + 255) / 256;
        weff_kernel<<<blocks, 256, 0, stream>>>(Wn, Wself, ker);
    }

    ConvIntrinsic_17102559772776_kernel<<<NBLK, 256, 0, stream>>>(mesh, bary, bias, d_out);
}